// Round 2
// baseline (221.472 us; speedup 1.0000x reference)
//
#include <hip/hip_runtime.h>
#include <hip/hip_bf16.h>

// Problem constants
#define SQn 2048
#define SKn 2048
#define DMn 1024
#define NHn 16
#define DHn 64

typedef __attribute__((ext_vector_type(8))) short bf16x8;
typedef __attribute__((ext_vector_type(4))) float f32x4;

__device__ __forceinline__ short f2bf(float f) {
  union { float f; unsigned u; } a; a.f = f;
  return (short)((a.u + 0x7FFFu + ((a.u >> 16) & 1u)) >> 16);  // RNE
}

__device__ __forceinline__ void gload16(const void* g, void* l) {
  __builtin_amdgcn_global_load_lds(
      (__attribute__((address_space(1))) void*)g,
      (__attribute__((address_space(3))) void*)l, 16, 0, 0);
}

// ---------------- elementwise f32 -> bf16 cast (vectorized, G13) ----------------
__global__ __launch_bounds__(256) void cast_f32_bf16(const float* __restrict__ in,
                                                     short* __restrict__ out, int n4) {
  int i = blockIdx.x * 256 + threadIdx.x;
  if (i >= n4) return;
  float4 f = ((const float4*)in)[i];
  short4 o;
  o.x = f2bf(f.x); o.y = f2bf(f.y); o.z = f2bf(f.z); o.w = f2bf(f.w);
  ((short4*)out)[i] = o;
}

// ---------------- W [K][N] f32  ->  Wt [N][K] bf16 ----------------
__global__ __launch_bounds__(256) void transpose_cast(const float* __restrict__ W,
                                                      short* __restrict__ Wt) {
  __shared__ float t[32][33];
  int bx = blockIdx.x * 32;  // N range
  int by = blockIdx.y * 32;  // K range
  int tx = threadIdx.x, ty = threadIdx.y;  // 32 x 8
#pragma unroll
  for (int j = 0; j < 4; ++j)
    t[ty + j * 8][tx] = W[(size_t)(by + ty + j * 8) * DMn + bx + tx];
  __syncthreads();
#pragma unroll
  for (int j = 0; j < 4; ++j)
    Wt[(size_t)(bx + ty + j * 8) * DMn + by + tx] = f2bf(t[tx][ty + j * 8]);
}

// ---------------- bf16 GEMM, m97 structure: C[M,N] = A[M,K] * Bt[N,K]^T + bias ----
// MODE 0: out bf16 scattered to [B][H][S][DH] (projection layout for attention)
// MODE 1: out f32 row-major [M][N] (final output)
// blockIdx.z selects one of up to 3 independent GEMMs (occupancy: 3 blocks/CU).
template <int MODE>
__global__ __launch_bounds__(256) void gemm_bt(
    const short* __restrict__ A0, const short* __restrict__ A1, const short* __restrict__ A2,
    const short* __restrict__ B0, const short* __restrict__ B1, const short* __restrict__ B2,
    const float* __restrict__ c0, const float* __restrict__ c1, const float* __restrict__ c2,
    void* __restrict__ O0, void* __restrict__ O1, void* __restrict__ O2) {
  constexpr int K = 1024, N = 1024;
  const int z = blockIdx.z;
  const short* A  = (z == 0) ? A0 : (z == 1) ? A1 : A2;
  const short* Bt = (z == 0) ? B0 : (z == 1) ? B1 : B2;
  const float* bias = (z == 0) ? c0 : (z == 1) ? c1 : c2;
  void* Cout = (z == 0) ? O0 : (z == 1) ? O1 : O2;

  __shared__ short As[128 * 32];
  __shared__ short Bs[128 * 32];
  const int tid = threadIdx.x;
  const int lane = tid & 63;
  const int wid = tid >> 6;
  const int wr = wid >> 1, wc = wid & 1;
  const int bm = blockIdx.x * 128, bn = blockIdx.y * 128;

  f32x4 acc[4][4] = {};

  const int srow = tid >> 2;            // 0..63 (16 rows per wave per call)
  const int scol = (tid & 3) * 8;       // 8 bf16 = 16B chunk
  const short* Ag = A + (size_t)bm * K;
  const short* Bg = Bt + (size_t)bn * K;

  for (int k0 = 0; k0 < K; k0 += 32) {
    __syncthreads();
    gload16(Ag + (size_t)srow * K + k0 + scol,        As + wid * 512);
    gload16(Ag + (size_t)(srow + 64) * K + k0 + scol, As + 2048 + wid * 512);
    gload16(Bg + (size_t)srow * K + k0 + scol,        Bs + wid * 512);
    gload16(Bg + (size_t)(srow + 64) * K + k0 + scol, Bs + 2048 + wid * 512);
    __syncthreads();

    bf16x8 a[4], b[4];
    const int rowA = wr * 64 + (lane & 15);
    const int rowB = wc * 64 + (lane & 15);
    const int ko = (lane >> 4) * 8;
#pragma unroll
    for (int m = 0; m < 4; ++m) a[m] = *(const bf16x8*)(As + (rowA + m * 16) * 32 + ko);
#pragma unroll
    for (int n = 0; n < 4; ++n) b[n] = *(const bf16x8*)(Bs + (rowB + n * 16) * 32 + ko);
#pragma unroll
    for (int m = 0; m < 4; ++m)
#pragma unroll
      for (int n = 0; n < 4; ++n)
        acc[m][n] = __builtin_amdgcn_mfma_f32_16x16x32_bf16(a[m], b[n], acc[m][n], 0, 0, 0);
  }

  // epilogue: C/D layout col=lane&15, row=(lane>>4)*4+i  [m89/m91 verified]
  const int crow0 = bm + wr * 64 + ((lane >> 4) * 4);
  const int ccol0 = bn + wc * 64 + (lane & 15);
#pragma unroll
  for (int m = 0; m < 4; ++m)
#pragma unroll
    for (int n = 0; n < 4; ++n) {
      int col = ccol0 + n * 16;
      float bv = bias[col];
#pragma unroll
      for (int i = 0; i < 4; ++i) {
        int row = crow0 + m * 16 + i;
        float val = acc[m][n][i] + bv;
        if (MODE == 0) {
          int bb = row >> 11, s = row & 2047;   // SQ=2048
          int hh = col >> 6, d = col & 63;      // DH=64
          ((short*)Cout)[((((size_t)bb * NHn + hh) * SQn + s) << 6) + d] = f2bf(val);
        } else {
          ((float*)Cout)[(size_t)row * N + col] = val;
        }
      }
    }
}

// ---------------- fused masked flash attention ----------------
// q,k,v: bf16 [B][H][S][64]; out: bf16 [B][S][H*64]
// grid: 1024 blocks = (b, h, 64-row q tile); 4 waves x 16 q rows each.
__global__ __launch_bounds__(256) void attn(const short* __restrict__ q,
                                            const short* __restrict__ k,
                                            const short* __restrict__ v,
                                            const int* __restrict__ mask,
                                            short* __restrict__ out) {
  __shared__ short Ks[64 * 64];      // linear, XOR-swizzled via pre-swizzled global src
  __shared__ short Vt[64 * 66];      // V^T [d][key], odd stride 66 -> conflict-free reads
  __shared__ short Ps[4][16 * 72];   // per-wave P tile [16 q][64 key], stride 72
  __shared__ float maskAdd[64];

  const int tid = threadIdx.x;
  const int lane = tid & 63;
  const int w = tid >> 6;
  const int qt = blockIdx.x & 31;
  const int h = (blockIdx.x >> 5) & 15;
  const int b = blockIdx.x >> 9;
  const size_t qko = ((size_t)b * NHn + h) * SQn * DHn;

  const int c_ = lane & 15, g_ = lane >> 4;

  // Q hoist: wave's 16 q rows live in registers for the whole kernel
  bf16x8 qf[2];
  {
    const short* qp = q + qko + (size_t)(qt * 64 + w * 16 + c_) * DHn + g_ * 8;
    qf[0] = *(const bf16x8*)qp;
    qf[1] = *(const bf16x8*)(qp + 32);
  }

  float mrun[4], lrun[4];
  f32x4 o[4] = {};
#pragma unroll
  for (int i = 0; i < 4; ++i) { mrun[i] = -1e30f; lrun[i] = 0.f; }

  for (int kt = 0; kt < SKn / 64; ++kt) {
    __syncthreads();
    {  // K tile: 2 x global_load_lds per thread, source chunk pre-swizzled ^(row&7)
      int r0 = w * 8 + (lane >> 3);
      int ch0 = (lane & 7) ^ (r0 & 7);
      gload16(k + qko + (size_t)(kt * 64 + r0) * DHn + ch0 * 8, Ks + w * 512);
      int r1 = 32 + r0;
      int ch1 = (lane & 7) ^ (r1 & 7);
      gload16(k + qko + (size_t)(kt * 64 + r1) * DHn + ch1 * 8, Ks + 2048 + w * 512);
    }
    {  // V tile transposed into Vt[d][key]
#pragma unroll
      for (int cc = 0; cc < 2; ++cc) {
        int key = cc * 32 + (tid >> 3);
        int oct = tid & 7;
        bf16x8 vv = *(const bf16x8*)(v + qko + (size_t)(kt * 64 + key) * DHn + oct * 8);
#pragma unroll
        for (int j = 0; j < 8; ++j) Vt[(oct * 8 + j) * 66 + key] = vv[j];
      }
    }
    if (tid < 64)
      maskAdd[tid] = mask[(size_t)b * SKn + kt * 64 + tid] ? 0.f : -1e30f;
    __syncthreads();

    // S = Q K^T  (A=Q regs, B-frag = K rows from swizzled LDS)
    f32x4 s[4];
#pragma unroll
    for (int n = 0; n < 4; ++n) {
      f32x4 accs = {};
      int key = n * 16 + c_;
#pragma unroll
      for (int kc = 0; kc < 2; ++kc) {
        int chunk = (kc * 4 + g_) ^ (key & 7);
        bf16x8 kf = *(const bf16x8*)(Ks + key * 64 + chunk * 8);
        accs = __builtin_amdgcn_mfma_f32_16x16x32_bf16(qf[kc], kf, accs, 0, 0, 0);
      }
      s[n] = accs;
    }
    // scale + additive mask
#pragma unroll
    for (int n = 0; n < 4; ++n) {
      float ma = maskAdd[n * 16 + c_];
#pragma unroll
      for (int i = 0; i < 4; ++i) s[n][i] = s[n][i] * 0.125f + ma;
    }
    // wave-parallel online softmax (rows span 16 lanes; reduce via shfl_xor)
    float sc[4];
#pragma unroll
    for (int i = 0; i < 4; ++i) {
      float rm = fmaxf(fmaxf(s[0][i], s[1][i]), fmaxf(s[2][i], s[3][i]));
#pragma unroll
      for (int off = 1; off < 16; off <<= 1) rm = fmaxf(rm, __shfl_xor(rm, off));
      float mn = fmaxf(mrun[i], rm);
      sc[i] = __expf(mrun[i] - mn);
      mrun[i] = mn;
    }
    float ps[4] = {0.f, 0.f, 0.f, 0.f};
    short* Pw = Ps[w];
#pragma unroll
    for (int n = 0; n < 4; ++n)
#pragma unroll
      for (int i = 0; i < 4; ++i) {
        float p = __expf(s[n][i] - mrun[i]);
        ps[i] += p;
        Pw[(g_ * 4 + i) * 72 + n * 16 + c_] = f2bf(p);
      }
#pragma unroll
    for (int i = 0; i < 4; ++i) {
      float t = ps[i];
#pragma unroll
      for (int off = 1; off < 16; off <<= 1) t += __shfl_xor(t, off);
      lrun[i] = lrun[i] * sc[i] + t;
    }
#pragma unroll
    for (int n = 0; n < 4; ++n)
#pragma unroll
      for (int i = 0; i < 4; ++i) o[n][i] *= sc[i];
    // O += P V   (A-frag = P from per-wave LDS, B-frag = Vt rows)
#pragma unroll
    for (int kc = 0; kc < 2; ++kc) {
      bf16x8 pf = *(const bf16x8*)(Pw + c_ * 72 + kc * 32 + g_ * 8);
#pragma unroll
      for (int n = 0; n < 4; ++n) {
        bf16x8 vf = *(const bf16x8*)(Vt + (n * 16 + c_) * 66 + kc * 32 + g_ * 8);
        o[n] = __builtin_amdgcn_mfma_f32_16x16x32_bf16(pf, vf, o[n], 0, 0, 0);
      }
    }
  }

  // out[b][s][h*64+d] = o / l
#pragma unroll
  for (int n = 0; n < 4; ++n)
#pragma unroll
    for (int i = 0; i < 4; ++i) {
      int srow = qt * 64 + w * 16 + g_ * 4 + i;
      int d = n * 16 + c_;
      out[((size_t)b * SQn + srow) * DMn + h * 64 + d] = f2bf(o[n][i] / lrun[i]);
    }
}

// ---------------- launch ----------------
extern "C" void kernel_launch(void* const* d_in, const int* in_sizes, int n_in,
                              void* d_out, int out_size, void* d_ws, size_t ws_size,
                              hipStream_t stream) {
  const float* Q  = (const float*)d_in[0];
  const float* K  = (const float*)d_in[1];
  const float* V  = (const float*)d_in[2];
  const int* mask = (const int*)d_in[3];
  const float* Wq = (const float*)d_in[4];
  const float* bq = (const float*)d_in[5];
  const float* Wk = (const float*)d_in[6];
  const float* bk = (const float*)d_in[7];
  const float* Wv = (const float*)d_in[8];
  const float* bv = (const float*)d_in[9];
  const float* Wo = (const float*)d_in[10];
  const float* bo = (const float*)d_in[11];

  char* ws = (char*)d_ws;
  const size_t MB = 1024 * 1024;
  short* Qb  = (short*)(ws + 0 * MB);    // 4M bf16 = 8MB each
  short* Kb  = (short*)(ws + 8 * MB);
  short* Vb  = (short*)(ws + 16 * MB);
  short* Wqt = (short*)(ws + 24 * MB);   // 1M bf16 = 2MB each
  short* Wkt = (short*)(ws + 26 * MB);
  short* Wvt = (short*)(ws + 28 * MB);
  short* Wot = (short*)(ws + 30 * MB);
  short* qp  = (short*)(ws + 32 * MB);   // [B][H][S][64]
  short* kp  = (short*)(ws + 40 * MB);
  short* vp  = (short*)(ws + 48 * MB);
  short* ao  = Qb;                       // alias: Qb dead after projection GEMM

  const int n4 = (2 * 2048 * 1024) / 4;  // 1048576
  cast_f32_bf16<<<n4 / 256, 256, 0, stream>>>(Q, Qb, n4);
  cast_f32_bf16<<<n4 / 256, 256, 0, stream>>>(K, Kb, n4);
  cast_f32_bf16<<<n4 / 256, 256, 0, stream>>>(V, Vb, n4);

  dim3 tb(32, 8);
  transpose_cast<<<dim3(32, 32), tb, 0, stream>>>(Wq, Wqt);
  transpose_cast<<<dim3(32, 32), tb, 0, stream>>>(Wk, Wkt);
  transpose_cast<<<dim3(32, 32), tb, 0, stream>>>(Wv, Wvt);
  transpose_cast<<<dim3(32, 32), tb, 0, stream>>>(Wo, Wot);

  // fused 3-way projection GEMM: grid.z picks q/k/v -> 768 blocks = 3 blocks/CU
  gemm_bt<0><<<dim3(32, 8, 3), 256, 0, stream>>>(Qb, Kb, Vb, Wqt, Wkt, Wvt,
                                                 bq, bk, bv, qp, kp, vp);

  attn<<<1024, 256, 0, stream>>>(qp, kp, vp, mask, ao);

  // final projection -> f32 output
  gemm_bt<1><<<dim3(32, 8, 1), 256, 0, stream>>>(ao, ao, ao, Wot, Wot, Wot,
                                                 bo, bo, bo, d_out, d_out, d_out);
}

// Round 3
// 198.767 us; speedup vs baseline: 1.1142x; 1.1142x over previous
//
#include <hip/hip_runtime.h>
#include <hip/hip_bf16.h>

// Problem constants
#define SQn 2048
#define SKn 2048
#define DMn 1024
#define NHn 16
#define DHn 64

typedef __attribute__((ext_vector_type(8))) short bf16x8;
typedef __attribute__((ext_vector_type(4))) float f32x4;

#define QSCALE 0.1803368801f  /* (1/sqrt(64)) / ln2 : folds softmax scale + exp->exp2 */

__device__ __forceinline__ short f2bf(float f) {
  union { float f; unsigned u; } a; a.f = f;
  return (short)((a.u + 0x7FFFu + ((a.u >> 16) & 1u)) >> 16);  // RNE
}

__device__ __forceinline__ void gload16(const void* g, void* l) {
  __builtin_amdgcn_global_load_lds(
      (__attribute__((address_space(1))) void*)g,
      (__attribute__((address_space(3))) void*)l, 16, 0, 0);
}

// ---------------- fused f32 -> bf16 cast for Q,K,V (one launch) ----------------
__global__ __launch_bounds__(256) void cast3_f32_bf16(const float* __restrict__ A,
                                                      const float* __restrict__ B,
                                                      const float* __restrict__ C,
                                                      short* __restrict__ out, int n4each) {
  int i = blockIdx.x * 256 + threadIdx.x;
  const float* src;
  int j = i;
  if (i < n4each) src = A;
  else if (i < 2 * n4each) { src = B; j = i - n4each; }
  else { src = C; j = i - 2 * n4each; }
  float4 f = ((const float4*)src)[j];
  short4 o;
  o.x = f2bf(f.x); o.y = f2bf(f.y); o.z = f2bf(f.z); o.w = f2bf(f.w);
  ((short4*)out)[i] = o;
}

// ---------------- W [K][N] f32 -> Wt [N][K] bf16, 4 weights in one launch --------
__global__ __launch_bounds__(256) void transpose_cast4(
    const float* __restrict__ W0, const float* __restrict__ W1,
    const float* __restrict__ W2, const float* __restrict__ W3,
    short* __restrict__ WtBase) {
  const int z = blockIdx.z;
  const float* W = (z == 0) ? W0 : (z == 1) ? W1 : (z == 2) ? W2 : W3;
  short* Wt = WtBase + (size_t)z * DMn * DMn;
  __shared__ float t[32][33];
  int bx = blockIdx.x * 32;  // N range
  int by = blockIdx.y * 32;  // K range
  int tx = threadIdx.x, ty = threadIdx.y;  // 32 x 8
#pragma unroll
  for (int j = 0; j < 4; ++j)
    t[ty + j * 8][tx] = W[(size_t)(by + ty + j * 8) * DMn + bx + tx];
  __syncthreads();
#pragma unroll
  for (int j = 0; j < 4; ++j)
    Wt[(size_t)(bx + ty + j * 8) * DMn + by + tx] = f2bf(t[tx][ty + j * 8]);
}

// ---------------- bf16 GEMM (m97 structure): C = A[M,K] * Bt[N,K]^T + bias -------
// MODE 0: projections. z=0 -> q scaled by QSCALE, [b][h][s][64]; z=1 -> k same
//         layout unscaled; z=2 -> V^T layout [b][h][d][s].
// MODE 1: f32 row-major output.
template <int MODE>
__global__ __launch_bounds__(256) void gemm_bt(
    const short* __restrict__ A0, const short* __restrict__ A1, const short* __restrict__ A2,
    const short* __restrict__ B0, const short* __restrict__ B1, const short* __restrict__ B2,
    const float* __restrict__ c0, const float* __restrict__ c1, const float* __restrict__ c2,
    void* __restrict__ O0, void* __restrict__ O1, void* __restrict__ O2) {
  constexpr int K = 1024, N = 1024;
  const int z = blockIdx.z;
  const short* A  = (z == 0) ? A0 : (z == 1) ? A1 : A2;
  const short* Bt = (z == 0) ? B0 : (z == 1) ? B1 : B2;
  const float* bias = (z == 0) ? c0 : (z == 1) ? c1 : c2;
  void* Cout = (z == 0) ? O0 : (z == 1) ? O1 : O2;

  __shared__ short As[128 * 32];
  __shared__ short Bs[128 * 32];
  const int tid = threadIdx.x;
  const int lane = tid & 63;
  const int wid = tid >> 6;
  const int wr = wid >> 1, wc = wid & 1;
  const int bm = blockIdx.x * 128, bn = blockIdx.y * 128;

  f32x4 acc[4][4] = {};

  const int srow = tid >> 2;
  const int scol = (tid & 3) * 8;
  const short* Ag = A + (size_t)bm * K;
  const short* Bg = Bt + (size_t)bn * K;

  for (int k0 = 0; k0 < K; k0 += 32) {
    __syncthreads();
    gload16(Ag + (size_t)srow * K + k0 + scol,        As + wid * 512);
    gload16(Ag + (size_t)(srow + 64) * K + k0 + scol, As + 2048 + wid * 512);
    gload16(Bg + (size_t)srow * K + k0 + scol,        Bs + wid * 512);
    gload16(Bg + (size_t)(srow + 64) * K + k0 + scol, Bs + 2048 + wid * 512);
    __syncthreads();

    bf16x8 a[4], b[4];
    const int rowA = wr * 64 + (lane & 15);
    const int rowB = wc * 64 + (lane & 15);
    const int ko = (lane >> 4) * 8;
#pragma unroll
    for (int m = 0; m < 4; ++m) a[m] = *(const bf16x8*)(As + (rowA + m * 16) * 32 + ko);
#pragma unroll
    for (int n = 0; n < 4; ++n) b[n] = *(const bf16x8*)(Bs + (rowB + n * 16) * 32 + ko);
#pragma unroll
    for (int m = 0; m < 4; ++m)
#pragma unroll
      for (int n = 0; n < 4; ++n)
        acc[m][n] = __builtin_amdgcn_mfma_f32_16x16x32_bf16(a[m], b[n], acc[m][n], 0, 0, 0);
  }

  // epilogue: C/D layout col=lane&15, row=(lane>>4)*4+i
  const int crow0 = bm + wr * 64 + ((lane >> 4) * 4);
  const int ccol0 = bn + wc * 64 + (lane & 15);
#pragma unroll
  for (int m = 0; m < 4; ++m)
#pragma unroll
    for (int n = 0; n < 4; ++n) {
      int col = ccol0 + n * 16;
      float bv = bias[col];
#pragma unroll
      for (int i = 0; i < 4; ++i) {
        int row = crow0 + m * 16 + i;
        float val = acc[m][n][i] + bv;
        if (MODE == 0) {
          int bb = row >> 11, s = row & 2047;   // SQ=2048
          int hh = col >> 6, d = col & 63;      // DH=64
          if (z == 2) {  // V^T: [b][h][d][s]
            ((short*)Cout)[((((size_t)bb * NHn + hh) * DHn + d) << 11) + s] = f2bf(val);
          } else {
            if (z == 0) val *= QSCALE;          // fold softmax scale into q
            ((short*)Cout)[((((size_t)bb * NHn + hh) * SQn + s) << 6) + d] = f2bf(val);
          }
        } else {
          ((float*)Cout)[(size_t)row * N + col] = val;
        }
      }
    }
}

// ---------------- fused masked flash attention, 128-key tiles ----------------
// q,k: bf16 [B][H][S][64] (q pre-scaled by QSCALE); vt: bf16 [B][H][64][S]
// out: bf16 [B][S][H*64].  grid: 1024 = (b, h, 64-row q tile); 4 waves x 16 q rows.
__global__ __launch_bounds__(256) void attn(const short* __restrict__ q,
                                            const short* __restrict__ k,
                                            const short* __restrict__ vt,
                                            const int* __restrict__ mask,
                                            short* __restrict__ out) {
  __shared__ short Ks[128 * 64];    // [key][d], chunk-swizzled ^(row&7)
  __shared__ short Vs[64 * 128];    // [d][key], chunk-swizzled ^(row&15)
  __shared__ short Ps[4][16 * 132]; // per-wave P [16 q][128 key], stride 132
  __shared__ float maskAdd[128];

  const int tid = threadIdx.x;
  const int lane = tid & 63;
  const int w = tid >> 6;
  const int qt = blockIdx.x & 31;
  const int h = (blockIdx.x >> 5) & 15;
  const int b = blockIdx.x >> 9;
  const size_t hoff = ((size_t)b * NHn + h) * (SQn * DHn);  // same flat size for k and vt

  const int c_ = lane & 15, g_ = lane >> 4;

  // Q hoist: wave's 16 q rows in registers (pre-scaled by QSCALE)
  bf16x8 qf[2];
  {
    const short* qp = q + hoff + (size_t)(qt * 64 + w * 16 + c_) * DHn + g_ * 8;
    qf[0] = *(const bf16x8*)qp;
    qf[1] = *(const bf16x8*)(qp + 32);
  }

  float mrun[4], lrun[4];
  f32x4 o[4] = {};
#pragma unroll
  for (int i = 0; i < 4; ++i) { mrun[i] = -1e30f; lrun[i] = 0.f; }

  short* Pw = Ps[w];

  for (int kt = 0; kt < SKn / 128; ++kt) {
    __syncthreads();
    // ---- stage K tile [128][64]: 1024 chunks, swizzle slot = gch ^ (row&7)
#pragma unroll
    for (int j = 0; j < 4; ++j) {
      int c = j * 256 + tid;
      int r = c >> 3, sl = c & 7;
      int gch = sl ^ (r & 7);
      gload16(k + hoff + (size_t)(kt * 128 + r) * 64 + gch * 8,
              Ks + (j * 256 + w * 64) * 8);
    }
    // ---- stage V^T tile [64][128]: 1024 chunks, swizzle slot = gch ^ (row&15)
#pragma unroll
    for (int j = 0; j < 4; ++j) {
      int c = j * 256 + tid;
      int r = c >> 4, sl = c & 15;
      int gch = sl ^ (r & 15);
      gload16(vt + hoff + (size_t)r * SKn + kt * 128 + gch * 8,
              Vs + (j * 256 + w * 64) * 8);
    }
    if (tid < 128)
      maskAdd[tid] = mask[(size_t)b * SKn + kt * 128 + tid] ? 0.f : -1e30f;
    __syncthreads();

    // ---- S = Q K^T (q pre-scaled; exp2 domain)
    f32x4 s[8];
    __builtin_amdgcn_s_setprio(1);
#pragma unroll
    for (int n = 0; n < 8; ++n) {
      f32x4 accs = {};
      int key = n * 16 + c_;
#pragma unroll
      for (int kc = 0; kc < 2; ++kc) {
        int slot = (kc * 4 + g_) ^ (key & 7);
        bf16x8 kf = *(const bf16x8*)(Ks + key * 64 + slot * 8);
        accs = __builtin_amdgcn_mfma_f32_16x16x32_bf16(qf[kc], kf, accs, 0, 0, 0);
      }
      s[n] = accs;
    }
    __builtin_amdgcn_s_setprio(0);

    // ---- additive mask
#pragma unroll
    for (int n = 0; n < 8; ++n) {
      float ma = maskAdd[n * 16 + c_];
#pragma unroll
      for (int i = 0; i < 4; ++i) s[n][i] += ma;
    }
    // ---- wave-parallel online softmax (rows span 16 lanes)
    float sc[4];
#pragma unroll
    for (int i = 0; i < 4; ++i) {
      float rm = s[0][i];
#pragma unroll
      for (int n = 1; n < 8; ++n) rm = fmaxf(rm, s[n][i]);
#pragma unroll
      for (int off = 1; off < 16; off <<= 1) rm = fmaxf(rm, __shfl_xor(rm, off));
      float mn = fmaxf(mrun[i], rm);
      sc[i] = __builtin_amdgcn_exp2f(mrun[i] - mn);
      mrun[i] = mn;
    }
    float ps[4] = {0.f, 0.f, 0.f, 0.f};
#pragma unroll
    for (int n = 0; n < 8; ++n)
#pragma unroll
      for (int i = 0; i < 4; ++i) {
        float p = __builtin_amdgcn_exp2f(s[n][i] - mrun[i]);
        ps[i] += p;
        Pw[(g_ * 4 + i) * 132 + n * 16 + c_] = f2bf(p);
      }
#pragma unroll
    for (int i = 0; i < 4; ++i) {
      float t = ps[i];
#pragma unroll
      for (int off = 1; off < 16; off <<= 1) t += __shfl_xor(t, off);
      lrun[i] = lrun[i] * sc[i] + t;
    }
#pragma unroll
    for (int n = 0; n < 4; ++n)
#pragma unroll
      for (int i = 0; i < 4; ++i) o[n][i] *= sc[i];

    // ---- O += P V  (A = P rows from LDS, B = V^T rows from swizzled LDS)
    __builtin_amdgcn_s_setprio(1);
#pragma unroll
    for (int ks = 0; ks < 4; ++ks) {
      bf16x8 pf = *(const bf16x8*)(Pw + c_ * 132 + ks * 32 + g_ * 8);
#pragma unroll
      for (int n = 0; n < 4; ++n) {
        int d = n * 16 + c_;
        int slot = (ks * 4 + g_) ^ (d & 15);
        bf16x8 vf = *(const bf16x8*)(Vs + d * 128 + slot * 8);
        o[n] = __builtin_amdgcn_mfma_f32_16x16x32_bf16(pf, vf, o[n], 0, 0, 0);
      }
    }
    __builtin_amdgcn_s_setprio(0);
  }

  // out[b][s][h*64+d] = o / l
#pragma unroll
  for (int n = 0; n < 4; ++n) {
#pragma unroll
    for (int i = 0; i < 4; ++i) {
      int srow = qt * 64 + w * 16 + g_ * 4 + i;
      int d = n * 16 + c_;
      out[((size_t)b * SQn + srow) * DMn + h * 64 + d] = f2bf(o[n][i] / lrun[i]);
    }
  }
}

// ---------------- launch ----------------
extern "C" void kernel_launch(void* const* d_in, const int* in_sizes, int n_in,
                              void* d_out, int out_size, void* d_ws, size_t ws_size,
                              hipStream_t stream) {
  const float* Q  = (const float*)d_in[0];
  const float* K  = (const float*)d_in[1];
  const float* V  = (const float*)d_in[2];
  const int* mask = (const int*)d_in[3];
  const float* Wq = (const float*)d_in[4];
  const float* bq = (const float*)d_in[5];
  const float* Wk = (const float*)d_in[6];
  const float* bk = (const float*)d_in[7];
  const float* Wv = (const float*)d_in[8];
  const float* bv = (const float*)d_in[9];
  const float* Wo = (const float*)d_in[10];
  const float* bo = (const float*)d_in[11];

  char* ws = (char*)d_ws;
  const size_t MB = 1024 * 1024;
  short* Qb  = (short*)(ws + 0 * MB);    // 3 x 8MB contiguous (fused cast out)
  short* Wqt = (short*)(ws + 24 * MB);   // 4 x 2MB contiguous (fused transpose out)
  short* Wkt = (short*)(ws + 26 * MB);
  short* Wvt = (short*)(ws + 28 * MB);
  short* Wot = (short*)(ws + 30 * MB);
  short* qp  = (short*)(ws + 32 * MB);   // [B][H][S][64], pre-scaled
  short* kp  = (short*)(ws + 40 * MB);   // [B][H][S][64]
  short* vpt = (short*)(ws + 48 * MB);   // [B][H][64][S]  (V^T)
  short* Kb  = Qb + 4 * MB;              // element offsets into fused cast region
  short* Vb  = Qb + 8 * MB;
  short* ao  = Qb;                       // alias: Qb dead after projection GEMM

  const int n4 = (2 * 2048 * 1024) / 4;  // per-tensor float4 count
  cast3_f32_bf16<<<3 * n4 / 256, 256, 0, stream>>>(Q, K, V, Qb, n4);

  transpose_cast4<<<dim3(32, 32, 4), dim3(32, 8), 0, stream>>>(Wq, Wk, Wv, Wo, Wqt);

  // fused 3-way projection GEMM (q scaled, V transposed in epilogue)
  gemm_bt<0><<<dim3(32, 8, 3), 256, 0, stream>>>(Qb, Kb, Vb, Wqt, Wkt, Wvt,
                                                 bq, bk, bv, qp, kp, vpt);

  attn<<<1024, 256, 0, stream>>>(qp, kp, vpt, mask, ao);

  // final projection -> f32 output
  gemm_bt<1><<<dim3(32, 8, 1), 256, 0, stream>>>(ao, ao, ao, Wot, Wot, Wot,
                                                 bo, bo, bo, d_out, d_out, d_out);
}

// Round 4
// 162.722 us; speedup vs baseline: 1.3610x; 1.2215x over previous
//
#include <hip/hip_runtime.h>
#include <hip/hip_bf16.h>

// Problem constants
#define SQn 2048
#define SKn 2048
#define DMn 1024
#define NHn 16
#define DHn 64

typedef __attribute__((ext_vector_type(8))) short bf16x8;
typedef __attribute__((ext_vector_type(4))) float f32x4;

#define QSCALE 0.1803368801f  /* (1/sqrt(64)) / ln2 : folds softmax scale + exp->exp2 */

__device__ __forceinline__ short f2bf(float f) {
  union { float f; unsigned u; } a; a.f = f;
  return (short)((a.u + 0x7FFFu + ((a.u >> 16) & 1u)) >> 16);  // RNE
}

__device__ __forceinline__ void gload16(const void* g, void* l) {
  __builtin_amdgcn_global_load_lds(
      (__attribute__((address_space(1))) void*)g,
      (__attribute__((address_space(3))) void*)l, 16, 0, 0);
}

// ---------------- fused f32 -> bf16 cast for Q,K,V (one launch) ----------------
__global__ __launch_bounds__(256) void cast3_f32_bf16(const float* __restrict__ A,
                                                      const float* __restrict__ B,
                                                      const float* __restrict__ C,
                                                      short* __restrict__ out, int n4each) {
  int i = blockIdx.x * 256 + threadIdx.x;
  const float* src;
  int j = i;
  if (i < n4each) src = A;
  else if (i < 2 * n4each) { src = B; j = i - n4each; }
  else { src = C; j = i - 2 * n4each; }
  float4 f = ((const float4*)src)[j];
  short4 o;
  o.x = f2bf(f.x); o.y = f2bf(f.y); o.z = f2bf(f.z); o.w = f2bf(f.w);
  ((short4*)out)[i] = o;
}

// ---------------- W [K][N] f32 -> Wt [N][K] bf16, 4 weights in one launch --------
__global__ __launch_bounds__(256) void transpose_cast4(
    const float* __restrict__ W0, const float* __restrict__ W1,
    const float* __restrict__ W2, const float* __restrict__ W3,
    short* __restrict__ WtBase) {
  const int z = blockIdx.z;
  const float* W = (z == 0) ? W0 : (z == 1) ? W1 : (z == 2) ? W2 : W3;
  short* Wt = WtBase + (size_t)z * DMn * DMn;
  __shared__ float t[32][33];
  int bx = blockIdx.x * 32;  // N range
  int by = blockIdx.y * 32;  // K range
  int tx = threadIdx.x, ty = threadIdx.y;  // 32 x 8
#pragma unroll
  for (int j = 0; j < 4; ++j)
    t[ty + j * 8][tx] = W[(size_t)(by + ty + j * 8) * DMn + bx + tx];
  __syncthreads();
#pragma unroll
  for (int j = 0; j < 4; ++j)
    Wt[(size_t)(bx + ty + j * 8) * DMn + by + tx] = f2bf(t[tx][ty + j * 8]);
}

// ---------------- bf16 GEMM (m97 structure): C = A[M,K] * Bt[N,K]^T + bias -------
// MODE 0: projections. z=0 -> q scaled by QSCALE, [b][h][s][64]; z=1 -> k same
//         layout unscaled; z=2 -> V^T layout [b][h][d][s].
// MODE 1: f32 row-major output.
template <int MODE>
__global__ __launch_bounds__(256) void gemm_bt(
    const short* __restrict__ A0, const short* __restrict__ A1, const short* __restrict__ A2,
    const short* __restrict__ B0, const short* __restrict__ B1, const short* __restrict__ B2,
    const float* __restrict__ c0, const float* __restrict__ c1, const float* __restrict__ c2,
    void* __restrict__ O0, void* __restrict__ O1, void* __restrict__ O2) {
  constexpr int K = 1024, N = 1024;
  const int z = blockIdx.z;
  const short* A  = (z == 0) ? A0 : (z == 1) ? A1 : A2;
  const short* Bt = (z == 0) ? B0 : (z == 1) ? B1 : B2;
  const float* bias = (z == 0) ? c0 : (z == 1) ? c1 : c2;
  void* Cout = (z == 0) ? O0 : (z == 1) ? O1 : O2;

  __shared__ short As[128 * 32];
  __shared__ short Bs[128 * 32];
  const int tid = threadIdx.x;
  const int lane = tid & 63;
  const int wid = tid >> 6;
  const int wr = wid >> 1, wc = wid & 1;
  const int bm = blockIdx.x * 128, bn = blockIdx.y * 128;

  f32x4 acc[4][4] = {};

  const int srow = tid >> 2;
  const int scol = (tid & 3) * 8;
  const short* Ag = A + (size_t)bm * K;
  const short* Bg = Bt + (size_t)bn * K;

  for (int k0 = 0; k0 < K; k0 += 32) {
    __syncthreads();
    gload16(Ag + (size_t)srow * K + k0 + scol,        As + wid * 512);
    gload16(Ag + (size_t)(srow + 64) * K + k0 + scol, As + 2048 + wid * 512);
    gload16(Bg + (size_t)srow * K + k0 + scol,        Bs + wid * 512);
    gload16(Bg + (size_t)(srow + 64) * K + k0 + scol, Bs + 2048 + wid * 512);
    __syncthreads();

    bf16x8 a[4], b[4];
    const int rowA = wr * 64 + (lane & 15);
    const int rowB = wc * 64 + (lane & 15);
    const int ko = (lane >> 4) * 8;
#pragma unroll
    for (int m = 0; m < 4; ++m) a[m] = *(const bf16x8*)(As + (rowA + m * 16) * 32 + ko);
#pragma unroll
    for (int n = 0; n < 4; ++n) b[n] = *(const bf16x8*)(Bs + (rowB + n * 16) * 32 + ko);
#pragma unroll
    for (int m = 0; m < 4; ++m)
#pragma unroll
      for (int n = 0; n < 4; ++n)
        acc[m][n] = __builtin_amdgcn_mfma_f32_16x16x32_bf16(a[m], b[n], acc[m][n], 0, 0, 0);
  }

  // epilogue: C/D layout col=lane&15, row=(lane>>4)*4+i
  const int crow0 = bm + wr * 64 + ((lane >> 4) * 4);
  const int ccol0 = bn + wc * 64 + (lane & 15);
#pragma unroll
  for (int m = 0; m < 4; ++m)
#pragma unroll
    for (int n = 0; n < 4; ++n) {
      int col = ccol0 + n * 16;
      float bv = bias[col];
#pragma unroll
      for (int i = 0; i < 4; ++i) {
        int row = crow0 + m * 16 + i;
        float val = acc[m][n][i] + bv;
        if (MODE == 0) {
          int bb = row >> 11, s = row & 2047;   // SQ=2048
          int hh = col >> 6, d = col & 63;      // DH=64
          if (z == 2) {  // V^T: [b][h][d][s]
            ((short*)Cout)[((((size_t)bb * NHn + hh) * DHn + d) << 11) + s] = f2bf(val);
          } else {
            if (z == 0) val *= QSCALE;          // fold softmax scale into q
            ((short*)Cout)[((((size_t)bb * NHn + hh) * SQn + s) << 6) + d] = f2bf(val);
          }
        } else {
          ((float*)Cout)[(size_t)row * N + col] = val;
        }
      }
    }
}

// ---------------- fused masked flash attention ----------------
// Swapped QK^T (lane owns one q row) + double-buffered K/V staging.
// q,k: bf16 [B][H][S][64] (q pre-scaled); vt: bf16 [B][H][64][S]
// out: bf16 [B][S][H*64]. grid 1024 = (b,h,64-row q tile); 4 waves x 16 q rows.
// LDS = 2*8K (K) + 2*8K (V) + 8K (P) = 40960 -> 4 blocks/CU, full co-residency.
__global__ __launch_bounds__(256, 4) void attn(const short* __restrict__ q,
                                               const short* __restrict__ k,
                                               const short* __restrict__ vt,
                                               const int* __restrict__ mask,
                                               short* __restrict__ out) {
  __shared__ short Ks[2][64 * 64];   // [key][d], chunk-swizzled ^(key&7)
  __shared__ short Vs[2][64 * 64];   // [d][key], chunk-swizzled ^(d&7)
  __shared__ short Ps[4][16 * 64];   // per-wave P [16 q][64 key], 8B-slot XOR swizzle

  const int tid = threadIdx.x;
  const int lane = tid & 63;
  const int w = tid >> 6;
  const int qt = blockIdx.x & 31;
  const int h = (blockIdx.x >> 5) & 15;
  const int b = blockIdx.x >> 9;
  const size_t hoff = ((size_t)b * NHn + h) * (SQn * DHn);

  const int c_ = lane & 15, g_ = lane >> 4;
  const int swz = (c_ & 7) << 4;         // P-buffer byte swizzle (bits 4-6)

  // Q hoist: serves as B-operand of swapped QK^T (A/B frags share lane layout)
  bf16x8 qf[2];
  {
    const short* qp = q + hoff + (size_t)(qt * 64 + w * 16 + c_) * DHn + g_ * 8;
    qf[0] = *(const bf16x8*)qp;
    qf[1] = *(const bf16x8*)(qp + 32);
  }

  const int* mrow = mask + (size_t)b * SKn;

  float mrun = -1e30f, lrun = 0.f;
  f32x4 o[4] = {};
  char* PwB = (char*)Ps[w];

  // ---- prologue: stage tile 0 into buf 0, mask tile 0 into regs ----
  int4 mnext[4];
  {
#pragma unroll
    for (int j = 0; j < 2; ++j) {
      int c = j * 256 + tid;
      int r = c >> 3, sl = c & 7;
      int gch = sl ^ (r & 7);
      gload16(k + hoff + (size_t)r * DHn + gch * 8, &Ks[0][(j * 256 + w * 64) * 8]);
    }
#pragma unroll
    for (int j = 0; j < 2; ++j) {
      int c = j * 256 + tid;
      int r = c >> 3, sl = c & 7;
      int gch = sl ^ (r & 7);
      gload16(vt + hoff + (size_t)r * SKn + gch * 8, &Vs[0][(j * 256 + w * 64) * 8]);
    }
#pragma unroll
    for (int n = 0; n < 4; ++n)
      mnext[n] = *(const int4*)(mrow + n * 16 + g_ * 4);
  }
  __syncthreads();

  int cur = 0;
  for (int kt = 0; kt < SKn / 64; ++kt) {
    int4 mcur[4];
#pragma unroll
    for (int n = 0; n < 4; ++n) mcur[n] = mnext[n];

    // ---- prefetch tile kt+1 into buf^1 (flies under this tile's compute) ----
    if (kt + 1 < SKn / 64) {
      const short* kb = k + hoff + (size_t)((kt + 1) * 64) * DHn;
      const short* vb = vt + hoff + (kt + 1) * 64;
      short* Kd = Ks[cur ^ 1];
      short* Vd = Vs[cur ^ 1];
#pragma unroll
      for (int j = 0; j < 2; ++j) {
        int c = j * 256 + tid;
        int r = c >> 3, sl = c & 7;
        int gch = sl ^ (r & 7);
        gload16(kb + (size_t)r * DHn + gch * 8, Kd + (j * 256 + w * 64) * 8);
      }
#pragma unroll
      for (int j = 0; j < 2; ++j) {
        int c = j * 256 + tid;
        int r = c >> 3, sl = c & 7;
        int gch = sl ^ (r & 7);
        gload16(vb + (size_t)r * SKn + gch * 8, Vd + (j * 256 + w * 64) * 8);
      }
#pragma unroll
      for (int n = 0; n < 4; ++n)
        mnext[n] = *(const int4*)(mrow + (kt + 1) * 64 + n * 16 + g_ * 4);
    }

    const short* Kc = Ks[cur];
    const short* Vc = Vs[cur];

    // ---- S^T = K Q^T : lane holds S[q=c_][key = 16n + 4g_ + i] ----
    f32x4 s[4];
    __builtin_amdgcn_s_setprio(1);
#pragma unroll
    for (int n = 0; n < 4; ++n) {
      f32x4 a = {};
      int key = n * 16 + c_;
#pragma unroll
      for (int kc = 0; kc < 2; ++kc) {
        int slot = (kc * 4 + g_) ^ (key & 7);
        bf16x8 kf = *(const bf16x8*)(Kc + key * 64 + slot * 8);
        a = __builtin_amdgcn_mfma_f32_16x16x32_bf16(kf, qf[kc], a, 0, 0, 0);
      }
      s[n] = a;
    }
    __builtin_amdgcn_s_setprio(0);

    // ---- mask select (regs, no LDS) ----
#pragma unroll
    for (int n = 0; n < 4; ++n) {
      s[n][0] = mcur[n].x ? s[n][0] : -1e30f;
      s[n][1] = mcur[n].y ? s[n][1] : -1e30f;
      s[n][2] = mcur[n].z ? s[n][2] : -1e30f;
      s[n][3] = mcur[n].w ? s[n][3] : -1e30f;
    }

    // ---- in-register online softmax for q = c_ ----
    float pm = s[0][0];
#pragma unroll
    for (int n = 0; n < 4; ++n) {
      pm = fmaxf(pm, fmaxf(fmaxf(s[n][0], s[n][1]), fmaxf(s[n][2], s[n][3])));
    }
    pm = fmaxf(pm, __shfl_xor(pm, 16));
    pm = fmaxf(pm, __shfl_xor(pm, 32));
    float mn = fmaxf(mrun, pm);
    float sc = __builtin_amdgcn_exp2f(mrun - mn);
    mrun = mn;

    float lsum = 0.f;
#pragma unroll
    for (int n = 0; n < 4; ++n) {
      float p0 = __builtin_amdgcn_exp2f(s[n][0] - mn);
      float p1 = __builtin_amdgcn_exp2f(s[n][1] - mn);
      float p2 = __builtin_amdgcn_exp2f(s[n][2] - mn);
      float p3 = __builtin_amdgcn_exp2f(s[n][3] - mn);
      lsum += (p0 + p1) + (p2 + p3);
      uint2 pk;
      pk.x = (unsigned)(unsigned short)f2bf(p0) | ((unsigned)(unsigned short)f2bf(p1) << 16);
      pk.y = (unsigned)(unsigned short)f2bf(p2) | ((unsigned)(unsigned short)f2bf(p3) << 16);
      // P[q=c_][keys 16n+4g_..+3], swizzled slot
      *(uint2*)(PwB + ((c_ * 128) | ((n * 32 + g_ * 8) ^ swz))) = pk;
    }
    lsum += __shfl_xor(lsum, 16);
    lsum += __shfl_xor(lsum, 32);
    lrun = lrun * sc + lsum;

    // ---- rescale O by sc of its rows (rows = g_*4+i live in lanes < 16) ----
    float scB[4];
#pragma unroll
    for (int i = 0; i < 4; ++i) scB[i] = __shfl(sc, g_ * 4 + i);
#pragma unroll
    for (int n = 0; n < 4; ++n)
#pragma unroll
      for (int i = 0; i < 4; ++i) o[n][i] *= scB[i];

    // ---- O += P V ----
    __builtin_amdgcn_s_setprio(1);
#pragma unroll
    for (int ks = 0; ks < 2; ++ks) {
      bf16x8 pf = *(const bf16x8*)(PwB + ((c_ * 128) | ((ks * 64 + g_ * 16) ^ swz)));
#pragma unroll
      for (int n = 0; n < 4; ++n) {
        int d = n * 16 + c_;
        int slot = (ks * 4 + g_) ^ (d & 7);
        bf16x8 vf = *(const bf16x8*)(Vc + d * 64 + slot * 8);
        o[n] = __builtin_amdgcn_mfma_f32_16x16x32_bf16(pf, vf, o[n], 0, 0, 0);
      }
    }
    __builtin_amdgcn_s_setprio(0);

    __syncthreads();   // drains prefetch vmcnt + P lgkm, flips buffers
    cur ^= 1;
  }

  // ---- epilogue: out[b][s][h*64+d] = o / l ----
  float lB[4];
#pragma unroll
  for (int i = 0; i < 4; ++i) lB[i] = __shfl(lrun, g_ * 4 + i);
#pragma unroll
  for (int n = 0; n < 4; ++n) {
#pragma unroll
    for (int i = 0; i < 4; ++i) {
      int srow = qt * 64 + w * 16 + g_ * 4 + i;
      int d = n * 16 + c_;
      out[((size_t)b * SQn + srow) * DMn + h * 64 + d] = f2bf(o[n][i] / lB[i]);
    }
  }
}

// ---------------- launch ----------------
extern "C" void kernel_launch(void* const* d_in, const int* in_sizes, int n_in,
                              void* d_out, int out_size, void* d_ws, size_t ws_size,
                              hipStream_t stream) {
  const float* Q  = (const float*)d_in[0];
  const float* K  = (const float*)d_in[1];
  const float* V  = (const float*)d_in[2];
  const int* mask = (const int*)d_in[3];
  const float* Wq = (const float*)d_in[4];
  const float* bq = (const float*)d_in[5];
  const float* Wk = (const float*)d_in[6];
  const float* bk = (const float*)d_in[7];
  const float* Wv = (const float*)d_in[8];
  const float* bv = (const float*)d_in[9];
  const float* Wo = (const float*)d_in[10];
  const float* bo = (const float*)d_in[11];

  char* ws = (char*)d_ws;
  const size_t MB = 1024 * 1024;
  short* Qb  = (short*)(ws + 0 * MB);    // 3 x 8MB contiguous (fused cast out)
  short* Wqt = (short*)(ws + 24 * MB);   // 4 x 2MB contiguous (fused transpose out)
  short* Wkt = (short*)(ws + 26 * MB);
  short* Wvt = (short*)(ws + 28 * MB);
  short* Wot = (short*)(ws + 30 * MB);
  short* qp  = (short*)(ws + 32 * MB);   // [B][H][S][64], pre-scaled
  short* kp  = (short*)(ws + 40 * MB);   // [B][H][S][64]
  short* vpt = (short*)(ws + 48 * MB);   // [B][H][64][S]  (V^T)
  short* Kb  = Qb + 4 * MB;              // element offsets into fused cast region
  short* Vb  = Qb + 8 * MB;
  short* ao  = Qb;                       // alias: Qb dead after projection GEMM

  const int n4 = (2 * 2048 * 1024) / 4;  // per-tensor float4 count
  cast3_f32_bf16<<<3 * n4 / 256, 256, 0, stream>>>(Q, K, V, Qb, n4);

  transpose_cast4<<<dim3(32, 32, 4), dim3(32, 8), 0, stream>>>(Wq, Wk, Wv, Wo, Wqt);

  // fused 3-way projection GEMM (q scaled, V transposed in epilogue)
  gemm_bt<0><<<dim3(32, 8, 3), 256, 0, stream>>>(Qb, Kb, Vb, Wqt, Wkt, Wvt,
                                                 bq, bk, bv, qp, kp, vpt);

  attn<<<1024, 256, 0, stream>>>(qp, kp, vpt, mask, ao);

  // final projection -> f32 output
  gemm_bt<1><<<dim3(32, 8, 1), 256, 0, stream>>>(ao, ao, ao, Wot, Wot, Wot,
                                                 bo, bo, bo, d_out, d_out, d_out);
}

// Round 6
// 147.634 us; speedup vs baseline: 1.5001x; 1.1022x over previous
//
#include <hip/hip_runtime.h>
#include <hip/hip_bf16.h>

// Problem constants
#define SQn 2048
#define SKn 2048
#define DMn 1024
#define NHn 16
#define DHn 64

typedef __attribute__((ext_vector_type(8))) short bf16x8;
typedef __attribute__((ext_vector_type(4))) float f32x4;

#define QSCALE 0.1803368801f  /* (1/sqrt(64)) / ln2 : folds softmax scale + exp->exp2 */

__device__ __forceinline__ short f2bf(float f) {
  union { float f; unsigned u; } a; a.f = f;
  return (short)((a.u + 0x7FFFu + ((a.u >> 16) & 1u)) >> 16);  // RNE
}

__device__ __forceinline__ unsigned cvt_pk_bf16(float lo, float hi) {
  unsigned r;
  asm("v_cvt_pk_bf16_f32 %0, %1, %2" : "=v"(r) : "v"(lo), "v"(hi));
  return r;
}

__device__ __forceinline__ void gload16(const void* g, void* l) {
  __builtin_amdgcn_global_load_lds(
      (__attribute__((address_space(1))) void*)g,
      (__attribute__((address_space(3))) void*)l, 16, 0, 0);
}

// ---------------- fused f32 -> bf16 cast for Q,K,V (one launch) ----------------
__global__ __launch_bounds__(256) void cast3_f32_bf16(const float* __restrict__ A,
                                                      const float* __restrict__ B,
                                                      const float* __restrict__ C,
                                                      short* __restrict__ out, int n4each) {
  int i = blockIdx.x * 256 + threadIdx.x;
  const float* src;
  int j = i;
  if (i < n4each) src = A;
  else if (i < 2 * n4each) { src = B; j = i - n4each; }
  else { src = C; j = i - 2 * n4each; }
  float4 f = ((const float4*)src)[j];
  short4 o;
  o.x = f2bf(f.x); o.y = f2bf(f.y); o.z = f2bf(f.z); o.w = f2bf(f.w);
  ((short4*)out)[i] = o;
}

// ---------------- W [K][N] f32 -> Wt [N][K] bf16, 4 weights in one launch --------
__global__ __launch_bounds__(256) void transpose_cast4(
    const float* __restrict__ W0, const float* __restrict__ W1,
    const float* __restrict__ W2, const float* __restrict__ W3,
    short* __restrict__ WtBase) {
  const int z = blockIdx.z;
  const float* W = (z == 0) ? W0 : (z == 1) ? W1 : (z == 2) ? W2 : W3;
  short* Wt = WtBase + (size_t)z * DMn * DMn;
  __shared__ float t[32][33];
  int bx = blockIdx.x * 32;  // N range
  int by = blockIdx.y * 32;  // K range
  int tx = threadIdx.x, ty = threadIdx.y;  // 32 x 8
#pragma unroll
  for (int j = 0; j < 4; ++j)
    t[ty + j * 8][tx] = W[(size_t)(by + ty + j * 8) * DMn + bx + tx];
  __syncthreads();
#pragma unroll
  for (int j = 0; j < 4; ++j)
    Wt[(size_t)(bx + ty + j * 8) * DMn + by + tx] = f2bf(t[tx][ty + j * 8]);
}

// ---------------- bf16 GEMM (m97 structure): C = A[M,K] * Bt[N,K]^T + bias -------
// Projections: z=0 -> q scaled by QSCALE, [b][h][s][64]; z=1 -> k same layout;
//              z=2 -> V^T layout [b][h][d][s].
__global__ __launch_bounds__(256) void gemm_bt3(
    const short* __restrict__ A0, const short* __restrict__ A1, const short* __restrict__ A2,
    const short* __restrict__ B0, const short* __restrict__ B1, const short* __restrict__ B2,
    const float* __restrict__ c0, const float* __restrict__ c1, const float* __restrict__ c2,
    short* __restrict__ O0, short* __restrict__ O1, short* __restrict__ O2) {
  constexpr int K = 1024;
  const int z = blockIdx.z;
  const short* A  = (z == 0) ? A0 : (z == 1) ? A1 : A2;
  const short* Bt = (z == 0) ? B0 : (z == 1) ? B1 : B2;
  const float* bias = (z == 0) ? c0 : (z == 1) ? c1 : c2;
  short* Cout = (z == 0) ? O0 : (z == 1) ? O1 : O2;

  __shared__ short As[128 * 32];
  __shared__ short Bs[128 * 32];
  const int tid = threadIdx.x;
  const int lane = tid & 63;
  const int wid = tid >> 6;
  const int wr = wid >> 1, wc = wid & 1;
  const int bm = blockIdx.x * 128, bn = blockIdx.y * 128;

  f32x4 acc[4][4] = {};

  const int srow = tid >> 2;
  const int scol = (tid & 3) * 8;
  const short* Ag = A + (size_t)bm * K;
  const short* Bg = Bt + (size_t)bn * K;

  for (int k0 = 0; k0 < K; k0 += 32) {
    __syncthreads();
    gload16(Ag + (size_t)srow * K + k0 + scol,        As + wid * 512);
    gload16(Ag + (size_t)(srow + 64) * K + k0 + scol, As + 2048 + wid * 512);
    gload16(Bg + (size_t)srow * K + k0 + scol,        Bs + wid * 512);
    gload16(Bg + (size_t)(srow + 64) * K + k0 + scol, Bs + 2048 + wid * 512);
    __syncthreads();

    bf16x8 a[4], b[4];
    const int rowA = wr * 64 + (lane & 15);
    const int rowB = wc * 64 + (lane & 15);
    const int ko = (lane >> 4) * 8;
#pragma unroll
    for (int m = 0; m < 4; ++m) a[m] = *(const bf16x8*)(As + (rowA + m * 16) * 32 + ko);
#pragma unroll
    for (int n = 0; n < 4; ++n) b[n] = *(const bf16x8*)(Bs + (rowB + n * 16) * 32 + ko);
#pragma unroll
    for (int m = 0; m < 4; ++m)
#pragma unroll
      for (int n = 0; n < 4; ++n)
        acc[m][n] = __builtin_amdgcn_mfma_f32_16x16x32_bf16(a[m], b[n], acc[m][n], 0, 0, 0);
  }

  // epilogue: C/D layout col=lane&15, row=(lane>>4)*4+i
  const int crow0 = bm + wr * 64 + ((lane >> 4) * 4);
  const int ccol0 = bn + wc * 64 + (lane & 15);
#pragma unroll
  for (int m = 0; m < 4; ++m)
#pragma unroll
    for (int n = 0; n < 4; ++n) {
      int col = ccol0 + n * 16;
      float bv = bias[col];
#pragma unroll
      for (int i = 0; i < 4; ++i) {
        int row = crow0 + m * 16 + i;
        float val = acc[m][n][i] + bv;
        int bb = row >> 11, s = row & 2047;   // SQ=2048
        int hh = col >> 6, d = col & 63;      // DH=64
        if (z == 2) {  // V^T: [b][h][d][s]
          Cout[((((size_t)bb * NHn + hh) * DHn + d) << 11) + s] = f2bf(val);
        } else {
          if (z == 0) val *= QSCALE;          // fold softmax scale into q
          Cout[((((size_t)bb * NHn + hh) * SQn + s) << 6) + d] = f2bf(val);
        }
      }
    }
}

// ---------------- final GEMM, 128x64 tile (512 blocks = 2/CU) -------------------
__global__ __launch_bounds__(256) void gemm_n64(const short* __restrict__ A,
                                                const short* __restrict__ Bt,
                                                const float* __restrict__ bias,
                                                float* __restrict__ C) {
  constexpr int K = 1024, N = 1024;
  __shared__ short As[128 * 32];
  __shared__ short Bs[64 * 32];
  const int tid = threadIdx.x;
  const int lane = tid & 63;
  const int wid = tid >> 6;
  const int wr = wid >> 1, wc = wid & 1;   // waves 2x2, wave tile 64x32
  const int bm = blockIdx.x * 128, bn = blockIdx.y * 64;

  f32x4 acc[4][2] = {};

  const int srow = tid >> 2;
  const int scol = (tid & 3) * 8;
  const short* Ag = A + (size_t)bm * K;
  const short* Bg = Bt + (size_t)bn * K;

  for (int k0 = 0; k0 < K; k0 += 32) {
    __syncthreads();
    gload16(Ag + (size_t)srow * K + k0 + scol,        As + wid * 512);
    gload16(Ag + (size_t)(srow + 64) * K + k0 + scol, As + 2048 + wid * 512);
    gload16(Bg + (size_t)srow * K + k0 + scol,        Bs + wid * 512);
    __syncthreads();

    bf16x8 a[4], b[2];
    const int rowA = wr * 64 + (lane & 15);
    const int rowB = wc * 32 + (lane & 15);
    const int ko = (lane >> 4) * 8;
#pragma unroll
    for (int m = 0; m < 4; ++m) a[m] = *(const bf16x8*)(As + (rowA + m * 16) * 32 + ko);
#pragma unroll
    for (int n = 0; n < 2; ++n) b[n] = *(const bf16x8*)(Bs + (rowB + n * 16) * 32 + ko);
#pragma unroll
    for (int m = 0; m < 4; ++m)
#pragma unroll
      for (int n = 0; n < 2; ++n)
        acc[m][n] = __builtin_amdgcn_mfma_f32_16x16x32_bf16(a[m], b[n], acc[m][n], 0, 0, 0);
  }

  const int crow0 = bm + wr * 64 + ((lane >> 4) * 4);
  const int ccol0 = bn + wc * 32 + (lane & 15);
#pragma unroll
  for (int m = 0; m < 4; ++m)
#pragma unroll
    for (int n = 0; n < 2; ++n) {
      int col = ccol0 + n * 16;
      float bv = bias[col];
#pragma unroll
      for (int i = 0; i < 4; ++i) {
        int row = crow0 + m * 16 + i;
        C[(size_t)row * N + col] = acc[m][n][i] + bv;
      }
    }
}

// ---------------- fused masked flash attention ----------------
// Swapped QK^T (lane owns one q row), double-buffered K/V, cvt_pk P-pack,
// defer-max rescale skip, XCD-aware head placement.
// LDS = 2*8K (K) + 2*8K (V) + 8K (P) = 40960 -> 4 blocks/CU.
__global__ __launch_bounds__(256, 4) void attn(const short* __restrict__ q,
                                               const short* __restrict__ k,
                                               const short* __restrict__ vt,
                                               const int* __restrict__ mask,
                                               short* __restrict__ out) {
  __shared__ short Ks[2][64 * 64];   // [key][d], chunk-swizzled ^(key&7)
  __shared__ short Vs[2][64 * 64];   // [d][key], chunk-swizzled ^(d&7)
  __shared__ short Ps[4][16 * 64];   // per-wave P [16 q][64 key], 8B-slot XOR swizzle

  const int tid = threadIdx.x;
  const int lane = tid & 63;
  const int w = tid >> 6;
  // XCD-aware remap: blocks on one XCD (virt&7 under round-robin dispatch)
  // cover 4 heads -> K/V working set 2MB fits that XCD's 4MB L2.
  const int virt = blockIdx.x;
  const int rest = virt >> 3;
  const int bh = (virt & 7) * 4 + (rest & 3);   // 0..31 = b*16+h
  const int qt = rest >> 2;                     // 0..31
  const int h = bh & 15;
  const int b = bh >> 4;
  const size_t hoff = (size_t)bh * (SQn * DHn);

  const int c_ = lane & 15, g_ = lane >> 4;
  const int swz = (c_ & 7) << 4;         // P-buffer byte swizzle (bits 4-6)

  // Q hoist (B-operand of swapped QK^T)
  bf16x8 qf[2];
  {
    const short* qp = q + hoff + (size_t)(qt * 64 + w * 16 + c_) * DHn + g_ * 8;
    qf[0] = *(const bf16x8*)qp;
    qf[1] = *(const bf16x8*)(qp + 32);
  }

  // staging geometry (loop-invariant per thread)
  const int c0i = tid, c1i = 256 + tid;
  const int r0 = c0i >> 3, gch0 = (c0i & 7) ^ (r0 & 7);
  const int r1 = c1i >> 3, gch1 = (c1i & 7) ^ (r1 & 7);
  const size_t kO0 = (size_t)r0 * DHn + gch0 * 8;
  const size_t kO1 = (size_t)r1 * DHn + gch1 * 8;
  const size_t vO0 = (size_t)r0 * SKn + gch0 * 8;
  const size_t vO1 = (size_t)r1 * SKn + gch1 * 8;
  const int ldsO0 = (w * 64) * 8;
  const int ldsO1 = (256 + w * 64) * 8;

  const int* mrow = mask + (size_t)b * SKn;

  float mrun = -1e30f, lrun = 0.f;
  f32x4 o[4] = {};
  char* PwB = (char*)Ps[w];

#define STAGE(buf, kbase, vbase)                    \
  gload16((kbase) + kO0, &Ks[buf][ldsO0]);          \
  gload16((kbase) + kO1, &Ks[buf][ldsO1]);          \
  gload16((vbase) + vO0, &Vs[buf][ldsO0]);          \
  gload16((vbase) + vO1, &Vs[buf][ldsO1]);

  // ---- prologue: stage tile 0 into buf 0, mask tile 0 into regs ----
  const short* kpre = k + hoff;
  const short* vpre = vt + hoff;
  int4 mnext[4];
  STAGE(0, kpre, vpre);
#pragma unroll
  for (int n = 0; n < 4; ++n) mnext[n] = *(const int4*)(mrow + n * 16 + g_ * 4);
  kpre += 64 * DHn;
  vpre += 64;
  const int* mpre = mrow + 64;
  __syncthreads();

  int cur = 0;
  for (int kt = 0; kt < SKn / 64; ++kt) {
    int4 mcur[4];
#pragma unroll
    for (int n = 0; n < 4; ++n) mcur[n] = mnext[n];

    // ---- prefetch tile kt+1 into buf^1 (flies under this tile's compute) ----
    if (kt + 1 < SKn / 64) {
      STAGE(cur ^ 1, kpre, vpre);
#pragma unroll
      for (int n = 0; n < 4; ++n) mnext[n] = *(const int4*)(mpre + n * 16 + g_ * 4);
      kpre += 64 * DHn;
      vpre += 64;
      mpre += 64;
    }

    const short* Kc = Ks[cur];
    const short* Vc = Vs[cur];

    // ---- S^T = K Q^T : lane holds S[q=c_][key = 16n + 4g_ + i] ----
    f32x4 s[4];
    __builtin_amdgcn_s_setprio(1);
#pragma unroll
    for (int n = 0; n < 4; ++n) {
      f32x4 a = {};
      int key = n * 16 + c_;
#pragma unroll
      for (int kc = 0; kc < 2; ++kc) {
        int slot = (kc * 4 + g_) ^ (key & 7);
        bf16x8 kf = *(const bf16x8*)(Kc + key * 64 + slot * 8);
        a = __builtin_amdgcn_mfma_f32_16x16x32_bf16(kf, qf[kc], a, 0, 0, 0);
      }
      s[n] = a;
    }
    __builtin_amdgcn_s_setprio(0);

    // ---- mask select (regs, no LDS) ----
#pragma unroll
    for (int n = 0; n < 4; ++n) {
      s[n][0] = mcur[n].x ? s[n][0] : -1e30f;
      s[n][1] = mcur[n].y ? s[n][1] : -1e30f;
      s[n][2] = mcur[n].z ? s[n][2] : -1e30f;
      s[n][3] = mcur[n].w ? s[n][3] : -1e30f;
    }

    // ---- online softmax, defer-max (T13): skip rescale when max didn't grow ----
    float pm = fmaxf(fmaxf(s[0][0], s[0][1]), fmaxf(s[0][2], s[0][3]));
#pragma unroll
    for (int n = 1; n < 4; ++n)
      pm = fmaxf(pm, fmaxf(fmaxf(s[n][0], s[n][1]), fmaxf(s[n][2], s[n][3])));
    pm = fmaxf(pm, __shfl_xor(pm, 16));
    pm = fmaxf(pm, __shfl_xor(pm, 32));

    if (!__all((pm - mrun <= 8.f) && (mrun > -1e29f))) {
      float mn = fmaxf(mrun, pm);
      float sc = __builtin_amdgcn_exp2f(mrun - mn);
      mrun = mn;
      lrun *= sc;
      float scB[4];
#pragma unroll
      for (int i = 0; i < 4; ++i) scB[i] = __shfl(sc, g_ * 4 + i);
#pragma unroll
      for (int n = 0; n < 4; ++n)
#pragma unroll
        for (int i = 0; i < 4; ++i) o[n][i] *= scB[i];
    }

    float lsum = 0.f;
#pragma unroll
    for (int n = 0; n < 4; ++n) {
      float p0 = __builtin_amdgcn_exp2f(s[n][0] - mrun);
      float p1 = __builtin_amdgcn_exp2f(s[n][1] - mrun);
      float p2 = __builtin_amdgcn_exp2f(s[n][2] - mrun);
      float p3 = __builtin_amdgcn_exp2f(s[n][3] - mrun);
      lsum += (p0 + p1) + (p2 + p3);
      uint2 pk;
      pk.x = cvt_pk_bf16(p0, p1);
      pk.y = cvt_pk_bf16(p2, p3);
      *(uint2*)(PwB + ((c_ * 128) | ((n * 32 + g_ * 8) ^ swz))) = pk;
    }
    lsum += __shfl_xor(lsum, 16);
    lsum += __shfl_xor(lsum, 32);
    lrun += lsum;

    // ---- O += P V ----
    __builtin_amdgcn_s_setprio(1);
#pragma unroll
    for (int ks = 0; ks < 2; ++ks) {
      bf16x8 pf = *(const bf16x8*)(PwB + ((c_ * 128) | ((ks * 64 + g_ * 16) ^ swz)));
#pragma unroll
      for (int n = 0; n < 4; ++n) {
        int d = n * 16 + c_;
        int slot = (ks * 4 + g_) ^ (d & 7);
        bf16x8 vf = *(const bf16x8*)(Vc + d * 64 + slot * 8);
        o[n] = __builtin_amdgcn_mfma_f32_16x16x32_bf16(pf, vf, o[n], 0, 0, 0);
      }
    }
    __builtin_amdgcn_s_setprio(0);

    __syncthreads();   // drains prefetch vmcnt + P lgkm, flips buffers
    cur ^= 1;
  }

  // ---- epilogue: out[b][s][h*64+d] = o / l ----
  float lB[4];
#pragma unroll
  for (int i = 0; i < 4; ++i) lB[i] = __shfl(lrun, g_ * 4 + i);
#pragma unroll
  for (int n = 0; n < 4; ++n) {
#pragma unroll
    for (int i = 0; i < 4; ++i) {
      int srow = qt * 64 + w * 16 + g_ * 4 + i;
      int d = n * 16 + c_;
      out[((size_t)b * SQn + srow) * DMn + h * 64 + d] = f2bf(o[n][i] / lB[i]);
    }
  }
#undef STAGE
}

// ---------------- launch ----------------
extern "C" void kernel_launch(void* const* d_in, const int* in_sizes, int n_in,
                              void* d_out, int out_size, void* d_ws, size_t ws_size,
                              hipStream_t stream) {
  const float* Q  = (const float*)d_in[0];
  const float* K  = (const float*)d_in[1];
  const float* V  = (const float*)d_in[2];
  const int* mask = (const int*)d_in[3];
  const float* Wq = (const float*)d_in[4];
  const float* bq = (const float*)d_in[5];
  const float* Wk = (const float*)d_in[6];
  const float* bk = (const float*)d_in[7];
  const float* Wv = (const float*)d_in[8];
  const float* bv = (const float*)d_in[9];
  const float* Wo = (const float*)d_in[10];
  const float* bo = (const float*)d_in[11];

  char* ws = (char*)d_ws;
  const size_t MB = 1024 * 1024;
  short* Qb  = (short*)(ws + 0 * MB);    // 3 x 8MB contiguous (fused cast out)
  short* Wqt = (short*)(ws + 24 * MB);   // 4 x 2MB contiguous (fused transpose out)
  short* Wkt = (short*)(ws + 26 * MB);
  short* Wvt = (short*)(ws + 28 * MB);
  short* Wot = (short*)(ws + 30 * MB);
  short* qp  = (short*)(ws + 32 * MB);   // [B][H][S][64], pre-scaled
  short* kp  = (short*)(ws + 40 * MB);   // [B][H][S][64]
  short* vpt = (short*)(ws + 48 * MB);   // [B][H][64][S]  (V^T)
  short* Kb  = Qb + 4 * MB;              // element offsets into fused cast region
  short* Vb  = Qb + 8 * MB;
  short* ao  = Qb;                       // alias: Qb dead after projection GEMM

  const int n4 = (2 * 2048 * 1024) / 4;  // per-tensor float4 count
  cast3_f32_bf16<<<3 * n4 / 256, 256, 0, stream>>>(Q, K, V, Qb, n4);

  transpose_cast4<<<dim3(32, 32, 4), dim3(32, 8), 0, stream>>>(Wq, Wk, Wv, Wo, Wqt);

  // fused 3-way projection GEMM (q scaled, V transposed in epilogue)
  gemm_bt3<<<dim3(32, 8, 3), 256, 0, stream>>>(Qb, Kb, Vb, Wqt, Wkt, Wvt,
                                               bq, bk, bv, qp, kp, vpt);

  attn<<<1024, 256, 0, stream>>>(qp, kp, vpt, mask, ao);

  // final projection -> f32 output, 128x64 tile = 512 blocks (2/CU)
  gemm_n64<<<dim3(32, 16), 256, 0, stream>>>(ao, Wot, bo, (float*)d_out);
}